// Round 10
// baseline (77.779 us; speedup 1.0000x reference)
//
#include <hip/hip_runtime.h>
#include <hip/hip_bf16.h>
#include <hip/hip_fp16.h>

// Problem constants (AttentionModule: B=16, idf=128, cdf=256, H=W=128, L=64)
#define NB  16
#define IDF 128
#define CDF 256
#define LL  64
#define PP  16384      // H*W pixels per batch
#define PXB 256        // pixels per tile -> 1KB store runs
#define XPITCH 260     // f32 pitch of the 16x256 transpose chunk

typedef _Float16 f16;
typedef _Float16 f16x4 __attribute__((ext_vector_type(4)));
typedef _Float16 f16x8 __attribute__((ext_vector_type(8)));
typedef float    f32x4 __attribute__((ext_vector_type(4)));

// Lightweight barrier: LDS-order only. Does NOT drain vmcnt -> in-flight
// global loads/stores keep streaming across chunk phases (HK pattern).
#define BAR() do { asm volatile("s_waitcnt lgkmcnt(0)" ::: "memory"); \
                   __builtin_amdgcn_s_barrier(); } while (0)

// ---------------------------------------------------------------------------
// Kernel 1 (merged prep): source = W @ context -> fp16 both orientations;
// block 0 also decodes the mask (int32 or uint8) into 16 x u64 bitmask.
// Mask row used by pixel p is p%16 (torch tile(mask,(P,1)) quirk, proven r2-9).
// ---------------------------------------------------------------------------
__global__ void src_pack_kernel(const float* __restrict__ Wm,
                                const float* __restrict__ ctx,
                                f16* __restrict__ srcF,
                                f16* __restrict__ srcT,
                                const unsigned char* __restrict__ mask_raw,
                                unsigned long long* __restrict__ mbits) {
    if (blockIdx.x == 0) {
        __shared__ int is_u8;
        const int tid = threadIdx.x;
        if (tid == 0) is_u8 = 0;
        if (tid < 16) mbits[tid] = 0ULL;
        __syncthreads();
        unsigned char byt[4];
        #pragma unroll
        for (int q = 0; q < 4; ++q) {
            int k = tid + q * 256;
            byt[q] = mask_raw[k];
            if ((k & 3) != 0 && byt[q] != 0) atomicOr(&is_u8, 1);
        }
        __syncthreads();
        #pragma unroll
        for (int q = 0; q < 4; ++q) {
            int k = tid + q * 256;
            int masked;
            if (is_u8) masked = (byt[q] != 0);
            else       masked = (((const int*)mask_raw)[k] != 0);
            if (masked) atomicOr(&mbits[k >> 6], 1ULL << (unsigned)(k & 63));
        }
    }

    int g = blockIdx.x * 256 + threadIdx.x;      // 0 .. NB*IDF*LL-1
    int l = g & (LL - 1);
    int i = (g >> 6) & (IDF - 1);
    int b = g >> 13;
    const float* wrow = Wm + (size_t)i * CDF;
    const float* ccol = ctx + (size_t)b * CDF * LL + l;
    float s = 0.f;
    #pragma unroll 8
    for (int c = 0; c < CDF; ++c)
        s = fmaf(wrow[c], ccol[(size_t)c * LL], s);
    f16 h = (f16)s;
    srcF[g] = h;                                 // [b][i][l]
    srcT[((size_t)b * LL + l) * IDF + i] = h;    // [b][l][i]
}

// ---------------------------------------------------------------------------
// Kernel 2 (main): block = 4 waves, TWO 256-px tiles (512 consecutive px).
// All 512 blocks co-resident (2/CU) -> single round. Tile 1's x loads are
// issued in the middle of tile 0's store-chunk pipeline (reads overlap
// writes); all barriers are lgkmcnt-only so stores/loads stay in flight.
// MFMA layouts identical to r6-r9 (verified).
// ---------------------------------------------------------------------------
__global__ __launch_bounds__(256, 2)
void attn_mfma_kernel(const float* __restrict__ x,
                      const f16* __restrict__ srcT,
                      const f16* __restrict__ srcF,
                      const unsigned long long* __restrict__ mbits,
                      float* __restrict__ weight,
                      float* __restrict__ attn_out) {
    __shared__ __align__(16) unsigned char s_srcT[LL * 256];    // [l][i] f16, swz
    __shared__ __align__(16) unsigned char s_srcF[IDF * 128];   // [i][l] f16, swz
    __shared__ __align__(16) unsigned char s_u[34816];          // prob / 2x xp

    float* s_xpA = (float*)s_u;                      // [16][XPITCH] f32
    float* s_xpB = (float*)(s_u + 16640);

    const int b    = blockIdx.y;
    const int tid  = threadIdx.x;
    const int wv   = tid >> 6;         // wave 0..3
    const int lane = tid & 63;
    const int c    = lane & 15;
    const int g    = lane >> 4;
    const int cs   = (c & 7) << 4;     // read-side XOR swizzle (bytes)

    f16* s_pw = (f16*)s_u + (size_t)wv * (64 * 68);  // per-wave prob [64px][68]

    // XCD swizzle: grid.x = 32 = 8 XCDs x 4 consecutive 512-px blocks
    const int bxs = (blockIdx.x & 7) * 4 + (blockIdx.x >> 3);
    const int pwb = bxs * (2 * PXB);                 // block pixel base (512)
    const float* xb0 = x + (size_t)b * IDF * PP + pwb + wv * 64 + c; // tile0
    const float* xb1 = xb0 + PXB;                                    // tile1

    // ---- mask bits for this lane's pixel rows (p%16 = 4g+r)
    unsigned mlo[4], mhi[4];
    #pragma unroll
    for (int r = 0; r < 4; ++r) {
        unsigned long long m = mbits[4 * g + r];
        mlo[r] = (unsigned)m;
        mhi[r] = (unsigned)(m >> 32);
    }

    float xfa[32], xfb[32];
    f16x8 xh0[4], xh1[4];
    f32x4 acc[4][4];
    f16x8 pa[4][2];

#define QK_LOAD(BUF, KS, XB)                                                \
    {   _Pragma("unroll")                                                   \
        for (int pt = 0; pt < 4; ++pt)                                      \
            _Pragma("unroll")                                               \
            for (int j = 0; j < 8; ++j)                                     \
                BUF[pt * 8 + j] =                                           \
                    (XB)[(size_t)((KS) * 32 + 8 * g + j) * PP + pt * 16];   \
    }

#define QK_CONV(BUF, XH)                                                    \
    {   _Pragma("unroll")                                                   \
        for (int pt = 0; pt < 4; ++pt)                                      \
            _Pragma("unroll")                                               \
            for (int j = 0; j < 8; ++j) XH[pt][j] = (f16)BUF[pt * 8 + j];   \
    }

#define QK_STEP_H(XH, KS)                                                   \
    {   _Pragma("unroll")                                                   \
        for (int nt = 0; nt < 4; ++nt) {                                    \
            const f16x8 bt = *reinterpret_cast<const f16x8*>(               \
                s_srcT + (nt * 16 + c) * 256 + (((KS) * 64 + 16 * g) ^ cs));\
            _Pragma("unroll")                                               \
            for (int pt = 0; pt < 4; ++pt)                                  \
                acc[pt][nt] = __builtin_amdgcn_mfma_f32_16x16x32_f16(       \
                    XH[pt], bt, acc[pt][nt], 0, 0, 0);                      \
        } }

#define QK_STEP(BUF, KS)                                                    \
    {   f16x8 xa_[4];                                                       \
        QK_CONV(BUF, xa_)                                                   \
        QK_STEP_H(xa_, KS) }

#define ACC_ZERO()                                                          \
    {   _Pragma("unroll")                                                   \
        for (int pt = 0; pt < 4; ++pt)                                      \
            _Pragma("unroll")                                               \
            for (int nt = 0; nt < 4; ++nt)                                  \
                acc[pt][nt] = (f32x4){0.f, 0.f, 0.f, 0.f}; }

#define SOFTMAX()                                                           \
    {   _Pragma("unroll")                                                   \
        for (int r = 0; r < 4; ++r) {                                       \
            const unsigned m0 = (mlo[r] >> c) & 1u;                         \
            const unsigned m1 = (mlo[r] >> (16 + c)) & 1u;                  \
            const unsigned m2 = (mhi[r] >> c) & 1u;                         \
            const unsigned m3 = (mhi[r] >> (16 + c)) & 1u;                  \
            _Pragma("unroll")                                               \
            for (int pt = 0; pt < 4; ++pt) {                                \
                if (m0) acc[pt][0][r] = -INFINITY;                          \
                if (m1) acc[pt][1][r] = -INFINITY;                          \
                if (m2) acc[pt][2][r] = -INFINITY;                          \
                if (m3) acc[pt][3][r] = -INFINITY;                          \
            }                                                               \
        }                                                                   \
        _Pragma("unroll")                                                   \
        for (int pt = 0; pt < 4; ++pt) {                                    \
            _Pragma("unroll")                                               \
            for (int r = 0; r < 4; ++r) {                                   \
                float mx = fmaxf(fmaxf(acc[pt][0][r], acc[pt][1][r]),       \
                                 fmaxf(acc[pt][2][r], acc[pt][3][r]));      \
                mx = fmaxf(mx, __shfl_xor(mx, 1, 64));                      \
                mx = fmaxf(mx, __shfl_xor(mx, 2, 64));                      \
                mx = fmaxf(mx, __shfl_xor(mx, 4, 64));                      \
                mx = fmaxf(mx, __shfl_xor(mx, 8, 64));                      \
                float sum = 0.f;                                            \
                _Pragma("unroll")                                           \
                for (int nt = 0; nt < 4; ++nt) {                            \
                    float e = exp2f((acc[pt][nt][r] - mx) * 1.44269504f);   \
                    acc[pt][nt][r] = e;                                     \
                    sum += e;                                               \
                }                                                           \
                sum += __shfl_xor(sum, 1, 64);                              \
                sum += __shfl_xor(sum, 2, 64);                              \
                sum += __shfl_xor(sum, 4, 64);                              \
                sum += __shfl_xor(sum, 8, 64);                              \
                const float inv = 1.f / sum;                                \
                _Pragma("unroll")                                           \
                for (int nt = 0; nt < 4; ++nt) acc[pt][nt][r] *= inv;       \
            }                                                               \
        } }

    // prob -> per-wave LDS tile (pitch 68 f16), read PV A-frags back
    // (same-wave RAW ordering, proven r4-r9).
#define PROB_EXCHANGE()                                                     \
    {   _Pragma("unroll")                                                   \
        for (int pt = 0; pt < 4; ++pt)                                      \
            _Pragma("unroll")                                               \
            for (int nt = 0; nt < 4; ++nt)                                  \
                _Pragma("unroll")                                           \
                for (int r = 0; r < 4; ++r)                                 \
                    s_pw[(pt * 16 + 4 * g + r) * 68 + nt * 16 + c] =        \
                        (f16)acc[pt][nt][r];                                \
        _Pragma("unroll")                                                   \
        for (int pt = 0; pt < 4; ++pt)                                      \
            _Pragma("unroll")                                               \
            for (int ks = 0; ks < 2; ++ks) {                                \
                const f16* pp = s_pw + (pt * 16 + c) * 68 + ks * 32 + 8 * g;\
                f16x4 lo = *reinterpret_cast<const f16x4*>(pp);             \
                f16x4 hi = *reinterpret_cast<const f16x4*>(pp + 4);         \
                f16x8 v;                                                    \
                _Pragma("unroll")                                           \
                for (int j = 0; j < 4; ++j) { v[j] = lo[j]; v[4+j] = hi[j]; } \
                pa[pt][ks] = v;                                             \
            } }

#define FILL_ATTN(NT, XP)                                                   \
    {   _Pragma("unroll")                                                   \
        for (int pt = 0; pt < 4; ++pt)                                      \
            *reinterpret_cast<f32x4*>(                                      \
                (XP) + c * XPITCH + wv * 64 + pt * 16 + 4 * g) = acc[pt][NT]; }

#define FILL_PV(CH, XP)                                                     \
    {   f32x4 a2[4];                                                        \
        _Pragma("unroll")                                                   \
        for (int pt = 0; pt < 4; ++pt) a2[pt] = (f32x4){0.f, 0.f, 0.f, 0.f};\
        _Pragma("unroll")                                                   \
        for (int ks = 0; ks < 2; ++ks) {                                    \
            const f16x8 sf = *reinterpret_cast<const f16x8*>(               \
                s_srcF + ((CH) * 16 + c) * 128 + ((ks * 64 + 16 * g) ^ cs));\
            _Pragma("unroll")                                               \
            for (int pt = 0; pt < 4; ++pt)                                  \
                a2[pt] = __builtin_amdgcn_mfma_f32_16x16x32_f16(            \
                    pa[pt][ks], sf, a2[pt], 0, 0, 0);                       \
        }                                                                   \
        _Pragma("unroll")                                                   \
        for (int pt = 0; pt < 4; ++pt)                                      \
            *reinterpret_cast<f32x4*>(                                      \
                (XP) + c * XPITCH + wv * 64 + pt * 16 + 4 * g) = a2[pt]; }

#define FILL_CHUNK(K, XP)                                                   \
    {   if ((K) < 4) { FILL_ATTN((K), (XP)) }                               \
        else         { FILL_PV((K) - 4, (XP)) } }

#define STORE_CHUNK(K, XP, AB, WB)                                          \
    {   float* dst = ((K) < 4)                                              \
            ? ((AB) + (size_t)((K) * 16) * PP)                              \
            : ((WB) + (size_t)(((K) - 4) * 16) * PP);                       \
        _Pragma("unroll")                                                   \
        for (int k2 = 0; k2 < 4; ++k2) {                                    \
            int f = tid + k2 * 256;                                         \
            int row = f >> 6, u = f & 63;                                   \
            f32x4 v = *reinterpret_cast<const f32x4*>(                      \
                (XP) + row * XPITCH + u * 4);                               \
            __builtin_nontemporal_store(v,                                  \
                reinterpret_cast<f32x4*>(dst + (size_t)row * PP + u * 4));  \
        } }

#define PIPE_STEP(K, CUR, NXT, AB, WB)                                      \
    STORE_CHUNK(K, CUR, AB, WB) FILL_CHUNK((K) + 1, NXT) BAR();

    // =========================== prologue ================================
    QK_LOAD(xfa, 0, xb0)     // first tile-0 loads before staging

    {   // stage srcT (16KB) + srcF (16KB) into LDS, write-side swizzled
        const f16* sT = srcT + (size_t)b * LL * IDF;
        const f16* sF = srcF + (size_t)b * IDF * LL;
        #pragma unroll
        for (int it = 0; it < 4; ++it) {
            int e = (it * 256 + tid) * 8;
            int l = e >> 7, i = e & 127;
            f16x8 v = *reinterpret_cast<const f16x8*>(sT + l * IDF + i);
            *reinterpret_cast<f16x8*>(
                s_srcT + l * 256 + ((i * 2) ^ ((l & 7) << 4))) = v;
        }
        #pragma unroll
        for (int it = 0; it < 4; ++it) {
            int e = (it * 256 + tid) * 8;
            int i = e >> 6, l = e & 63;
            f16x8 v = *reinterpret_cast<const f16x8*>(sF + i * LL + l);
            *reinterpret_cast<f16x8*>(
                s_srcF + i * 128 + ((l * 2) ^ ((i & 7) << 4))) = v;
        }
    }
    BAR();   // B0: staging done

    // =========================== tile 0 QK^T =============================
    ACC_ZERO()
    QK_LOAD(xfb, 1, xb0)
    QK_STEP(xfa, 0)
    QK_LOAD(xfa, 2, xb0)
    QK_STEP(xfb, 1)
    QK_LOAD(xfb, 3, xb0)
    QK_STEP(xfa, 2)
    QK_STEP(xfb, 3)
    SOFTMAX()
    PROB_EXCHANGE()
    BAR();   // B1: prob readbacks done; s_u becomes xp buffers

    float* abase0 = attn_out + (size_t)b * LL * PP + pwb;
    float* wbase0 = weight + (size_t)b * IDF * PP + pwb;
    float* abase1 = abase0 + PXB;
    float* wbase1 = wbase0 + PXB;

    // =================== tile 0 chunk pipeline (12) ======================
    FILL_CHUNK(0, s_xpA)
    BAR();
    PIPE_STEP(0, s_xpA, s_xpB, abase0, wbase0)
    PIPE_STEP(1, s_xpB, s_xpA, abase0, wbase0)
    PIPE_STEP(2, s_xpA, s_xpB, abase0, wbase0)   // FILL(3) = last acc use
    // acc dead -> issue tile-1 x loads ks0/ks1 (overlap reads with stores)
    QK_LOAD(xfa, 0, xb1)
    QK_LOAD(xfb, 1, xb1)
    PIPE_STEP(3, s_xpB, s_xpA, abase0, wbase0)
    PIPE_STEP(4, s_xpA, s_xpB, abase0, wbase0)
    PIPE_STEP(5, s_xpB, s_xpA, abase0, wbase0)
    PIPE_STEP(6, s_xpA, s_xpB, abase0, wbase0)
    // ks0/ks1 arrived long ago: convert, then issue ks2/ks3
    QK_CONV(xfa, xh0)
    QK_CONV(xfb, xh1)
    QK_LOAD(xfa, 2, xb1)
    QK_LOAD(xfb, 3, xb1)
    PIPE_STEP(7, s_xpB, s_xpA, abase0, wbase0)
    PIPE_STEP(8, s_xpA, s_xpB, abase0, wbase0)
    PIPE_STEP(9, s_xpB, s_xpA, abase0, wbase0)
    PIPE_STEP(10, s_xpA, s_xpB, abase0, wbase0)
    STORE_CHUNK(11, s_xpB, abase0, wbase0)
    BAR();   // all tile-0 xp reads done; s_u free for tile-1 prob

    // =========================== tile 1 QK^T =============================
    ACC_ZERO()
    QK_STEP_H(xh0, 0)
    QK_STEP_H(xh1, 1)
    QK_STEP(xfa, 2)
    QK_STEP(xfb, 3)
    SOFTMAX()
    PROB_EXCHANGE()
    BAR();   // prob readbacks done; s_u becomes xp buffers again

    // =================== tile 1 chunk pipeline (12) ======================
    FILL_CHUNK(0, s_xpA)
    BAR();
    PIPE_STEP(0, s_xpA, s_xpB, abase1, wbase1)
    PIPE_STEP(1, s_xpB, s_xpA, abase1, wbase1)
    PIPE_STEP(2, s_xpA, s_xpB, abase1, wbase1)
    PIPE_STEP(3, s_xpB, s_xpA, abase1, wbase1)
    PIPE_STEP(4, s_xpA, s_xpB, abase1, wbase1)
    PIPE_STEP(5, s_xpB, s_xpA, abase1, wbase1)
    PIPE_STEP(6, s_xpA, s_xpB, abase1, wbase1)
    PIPE_STEP(7, s_xpB, s_xpA, abase1, wbase1)
    PIPE_STEP(8, s_xpA, s_xpB, abase1, wbase1)
    PIPE_STEP(9, s_xpB, s_xpA, abase1, wbase1)
    PIPE_STEP(10, s_xpA, s_xpB, abase1, wbase1)
    STORE_CHUNK(11, s_xpB, abase1, wbase1)
    // kernel end: implicit full waitcnt drains stores
}

// ---------------------------------------------------------------------------
extern "C" void kernel_launch(void* const* d_in, const int* in_sizes, int n_in,
                              void* d_out, int out_size, void* d_ws, size_t ws_size,
                              hipStream_t stream) {
    const float*         x        = (const float*)d_in[0];
    const float*         ctx      = (const float*)d_in[1];
    const float*         Wm       = (const float*)d_in[2];
    const unsigned char* mask_raw = (const unsigned char*)d_in[3];

    float* weight   = (float*)d_out;                     // [B, IDF, H, W]
    float* attn_out = weight + (size_t)NB * IDF * PP;    // [B, L, H, W]

    // workspace: mbits u64[16] | srcF fp16 (256KB) | srcT fp16 (256KB)
    unsigned long long* mbits = (unsigned long long*)d_ws;
    f16* srcF = (f16*)((char*)d_ws + 4096);
    f16* srcT = srcF + (size_t)NB * IDF * LL;

    src_pack_kernel<<<(NB * IDF * LL) / 256, 256, 0, stream>>>(
        Wm, ctx, srcF, srcT, mask_raw, mbits);

    dim3 grid(PP / (2 * PXB), NB);
    attn_mfma_kernel<<<grid, 256, 0, stream>>>(x, srcT, srcF, mbits, weight, attn_out);
}